// Round 4
// baseline (242.342 us; speedup 1.0000x reference)
//
#include <hip/hip_runtime.h>
#include <hip/hip_bf16.h>

// OneStep: out = W - c * K^T (K W - V),  c = 0.2/(CTX*D) = 9.5367431640625e-8
// W:(4096,4096) K:(512,4096) V:(512,4096) fp32 -> out (4096,4096) fp32.
// bf16 MFMA w/ fp32 acc => absmax 2.441e-4 = 1 bf16 ulp (threshold 1.69e-3).
//
// R3 post-mortem: k2 (64x64 tiles) ran at 2.6 TB/s with 82 MB writes for a
// 64 MB output (partial-line epilogue) and MfmaUtil 12%; k1 at ~344 TF
// (m90-class 64^2 ceiling). R4: 128-tiles (m93/m97 structure), LDS-transposed
// float4 epilogue in k2, BK=64 in k1, XCD-pinned Wt reuse.

typedef __bf16 bf16_t;
typedef __bf16 bf16x8 __attribute__((ext_vector_type(8)));
typedef float f32x4 __attribute__((ext_vector_type(4)));

#define D_DIM 4096
#define CTX_N 512
#define UPD_SCALE 9.5367431640625e-8f

__device__ __forceinline__ void gld16(const bf16_t* g, bf16_t* l) {
    __builtin_amdgcn_global_load_lds(
        (const __attribute__((address_space(1))) void*)g,
        (__attribute__((address_space(3))) void*)l, 16, 0, 0);
}

// ---- transpose+convert body: src (M x N) fp32 -> dstT (N x M) bf16
//      [+ dstN (M x N) bf16].  64x64 tiles, pad-65 LDS (2-way = free). ----
__device__ __forceinline__ void t_body(
    const float* __restrict__ src, bf16_t* __restrict__ dstT,
    bf16_t* __restrict__ dstN, int M, int N)
{
    __shared__ float tile[64 * 65];
    const int tid = threadIdx.x;
    const int C0 = blockIdx.x * 64;   // col base (N dim)
    const int R0 = blockIdx.y * 64;   // row base (M dim)
    const int r  = tid >> 2, cs = (tid & 3) * 16;

    const float* s = src + (size_t)(R0 + r) * N + C0 + cs;
    float f[16];
#pragma unroll
    for (int u = 0; u < 4; ++u) {
        const float4 v = ((const float4*)s)[u];
        f[4 * u + 0] = v.x; f[4 * u + 1] = v.y; f[4 * u + 2] = v.z; f[4 * u + 3] = v.w;
    }
#pragma unroll
    for (int u = 0; u < 16; ++u) tile[r * 65 + cs + u] = f[u];

    if (dstN) {
        bf16x8 v0, v1;
#pragma unroll
        for (int u = 0; u < 8; ++u) { v0[u] = (bf16_t)f[u]; v1[u] = (bf16_t)f[8 + u]; }
        bf16_t* d = dstN + (size_t)(R0 + r) * N + C0 + cs;
        *(bf16x8*)d = v0; *(bf16x8*)(d + 8) = v1;
    }
    __syncthreads();

    bf16x8 o0, o1;
#pragma unroll
    for (int u = 0; u < 8; ++u) {
        o0[u] = (bf16_t)tile[(cs + u) * 65 + r];
        o1[u] = (bf16_t)tile[(cs + 8 + u) * 65 + r];
    }
    bf16_t* d = dstT + (size_t)(C0 + r) * M + R0 + cs;
    *(bf16x8*)d = o0; *(bf16x8*)(d + 8) = o1;
}

__global__ __launch_bounds__(256) void t_conv_w(
    const float* __restrict__ W, bf16_t* __restrict__ Wt)
{
    t_body(W, Wt, nullptr, D_DIM, D_DIM);
}

__global__ __launch_bounds__(256) void t_conv_kv(
    const float* __restrict__ K, const float* __restrict__ V,
    bf16_t* __restrict__ Kt, bf16_t* __restrict__ Kb, bf16_t* __restrict__ Vt)
{
    if (blockIdx.z == 0) t_body(K, Kt, Kb, CTX_N, D_DIM);
    else                 t_body(V, Vt, nullptr, CTX_N, D_DIM);
}

// MFMA 16x16x32 bf16 (m89/m91): A/B frag: row=lane&15, k=quad*8+j (8 bf16);
// C/D: col=lane&15, row=quad*4+reg.  D[m][n] = sum_k A(m,k)*B(n,k).

// ---- K1: Rt[j][c] = sum_k Wt[j][k]*Kb[c][k] - Vt[j][c]  (4096 x 512) ----
// 128(j) x 64(c) tile, BK=64, 4 waves of 64x32, 256 blocks (1/CU).
__global__ __launch_bounds__(256) void k1_residual(
    const bf16_t* __restrict__ Wt, const bf16_t* __restrict__ Kb,
    const bf16_t* __restrict__ Vt, bf16_t* __restrict__ Rt)
{
    __shared__ __align__(16) bf16_t As[128 * 64];  // Wt rows (j,k) 16 KB
    __shared__ __align__(16) bf16_t Bs[64 * 64];   // Kb rows (c,k)  8 KB

    const int tid = threadIdx.x;
    const int j0 = blockIdx.x * 128;  // bx%8 pins the 8 c-sharers to one XCD
    const int c0 = blockIdx.y * 64;
    const int lane = tid & 63, wave = tid >> 6;
    const int wi = (wave >> 1) * 64, wc = (wave & 1) * 32;
    const int l15 = lane & 15, quad = lane >> 4;

    f32x4 acc[4][2] = {};

    // staging: LDS offset = tid*16 B per call (wave-uniform base + lane*16)
    const bf16_t* ga = Wt + (size_t)(j0 + (tid >> 3)) * D_DIM + (tid & 7) * 8;
    const bf16_t* gb = Kb + (size_t)(c0 + (tid >> 3)) * D_DIM + (tid & 7) * 8;
    bf16_t* la = (bf16_t*)((char*)As + tid * 16);
    bf16_t* lb = (bf16_t*)((char*)Bs + tid * 16);

    for (int kk = 0; kk < D_DIM; kk += 64) {
#pragma unroll
        for (int c = 0; c < 4; ++c)
            gld16(ga + kk + (size_t)(c * 32) * D_DIM, la + c * 2048);
#pragma unroll
        for (int c = 0; c < 2; ++c)
            gld16(gb + kk + (size_t)(c * 32) * D_DIM, lb + c * 2048);
        __syncthreads();
#pragma unroll
        for (int kh = 0; kh < 2; ++kh) {
            bf16x8 a[4], b[2];
#pragma unroll
            for (int mi = 0; mi < 4; ++mi)
                a[mi] = *(const bf16x8*)(As + (wi + mi * 16 + l15) * 64 + kh * 32 + quad * 8);
#pragma unroll
            for (int ni = 0; ni < 2; ++ni)
                b[ni] = *(const bf16x8*)(Bs + (wc + ni * 16 + l15) * 64 + kh * 32 + quad * 8);
#pragma unroll
            for (int mi = 0; mi < 4; ++mi)
#pragma unroll
                for (int ni = 0; ni < 2; ++ni)
                    acc[mi][ni] = __builtin_amdgcn_mfma_f32_16x16x32_bf16(
                        a[mi], b[ni], acc[mi][ni], 0, 0, 0);
        }
        __syncthreads();
    }

#pragma unroll
    for (int mi = 0; mi < 4; ++mi)
#pragma unroll
        for (int ni = 0; ni < 2; ++ni)
#pragma unroll
            for (int r = 0; r < 4; ++r) {
                const int j = j0 + wi + mi * 16 + quad * 4 + r;
                const int c = c0 + wc + ni * 16 + l15;
                const size_t idx = (size_t)j * CTX_N + c;
                Rt[idx] = (bf16_t)(acc[mi][ni][r] - (float)Vt[idx]);
            }
}

// ---- K2: out[i][j] = W[i][j] - c * sum_c Kt[i][c]*Rt[j][c]  (4096x4096) ----
// 128x128 tile, BK=32, 4 waves of 64x64 (m93/m97 structure), 1024 blocks.
// Epilogue: acc -> ep[64][132] -> float4 W load + float4 out store.
__global__ __launch_bounds__(256) void k2_update(
    const bf16_t* __restrict__ Kt, const bf16_t* __restrict__ Rt,
    const float* __restrict__ W, float* __restrict__ out)
{
    __shared__ __align__(16) bf16_t As[128 * 32];  // Kt rows (i,c) 8 KB
    __shared__ __align__(16) bf16_t Bs[128 * 32];  // Rt rows (j,c) 8 KB
    __shared__ __align__(16) float  ep[64 * 132];  // 33 KB epilogue transpose

    const int tid = threadIdx.x;
    const int j0 = blockIdx.x * 128, i0 = blockIdx.y * 128;
    const int lane = tid & 63, wave = tid >> 6;
    const int wi = (wave >> 1) * 64, wj = (wave & 1) * 64;
    const int l15 = lane & 15, quad = lane >> 4;

    f32x4 acc[4][4] = {};

    const bf16_t* ga = Kt + (size_t)(i0 + (tid >> 2)) * CTX_N + (tid & 3) * 8;
    const bf16_t* gb = Rt + (size_t)(j0 + (tid >> 2)) * CTX_N + (tid & 3) * 8;
    bf16_t* la = (bf16_t*)((char*)As + tid * 16);
    bf16_t* lb = (bf16_t*)((char*)Bs + tid * 16);

    for (int cc = 0; cc < CTX_N; cc += 32) {
        gld16(ga + cc, la);
        gld16(ga + cc + (size_t)64 * CTX_N, la + 64 * 32);
        gld16(gb + cc, lb);
        gld16(gb + cc + (size_t)64 * CTX_N, lb + 64 * 32);
        __syncthreads();
        bf16x8 a[4], b[4];
#pragma unroll
        for (int mi = 0; mi < 4; ++mi)
            a[mi] = *(const bf16x8*)(As + (wi + mi * 16 + l15) * 32 + quad * 8);
#pragma unroll
        for (int ni = 0; ni < 4; ++ni)
            b[ni] = *(const bf16x8*)(Bs + (wj + ni * 16 + l15) * 32 + quad * 8);
#pragma unroll
        for (int mi = 0; mi < 4; ++mi)
#pragma unroll
            for (int ni = 0; ni < 4; ++ni)
                acc[mi][ni] = __builtin_amdgcn_mfma_f32_16x16x32_bf16(
                    a[mi], b[ni], acc[mi][ni], 0, 0, 0);
        __syncthreads();
    }

    // Epilogue: two 64-row passes through ep.
#pragma unroll
    for (int p = 0; p < 2; ++p) {
        if ((wave >> 1) == p) {
#pragma unroll
            for (int mi = 0; mi < 4; ++mi)
#pragma unroll
                for (int ni = 0; ni < 4; ++ni)
#pragma unroll
                    for (int r = 0; r < 4; ++r)
                        ep[(mi * 16 + quad * 4 + r) * 132 + wj + ni * 16 + l15] =
                            acc[mi][ni][r];
        }
        __syncthreads();
        {
            const int row = tid >> 2, cb = (tid & 3) * 32;
            const float* wrow = W   + (size_t)(i0 + p * 64 + row) * D_DIM + j0 + cb;
            float*      orow = out + (size_t)(i0 + p * 64 + row) * D_DIM + j0 + cb;
            const float* erow = ep + row * 132 + cb;
#pragma unroll
            for (int u = 0; u < 8; ++u) {
                const float4 wv = ((const float4*)wrow)[u];
                const float4 ev = ((const float4*)erow)[u];
                float4 ov;
                ov.x = wv.x - UPD_SCALE * ev.x;
                ov.y = wv.y - UPD_SCALE * ev.y;
                ov.z = wv.z - UPD_SCALE * ev.z;
                ov.w = wv.w - UPD_SCALE * ev.w;
                ((float4*)orow)[u] = ov;
            }
        }
        __syncthreads();
    }
}

extern "C" void kernel_launch(void* const* d_in, const int* in_sizes, int n_in,
                              void* d_out, int out_size, void* d_ws, size_t ws_size,
                              hipStream_t stream) {
    const float* W = (const float*)d_in[0];   // (4096, 4096)
    const float* K = (const float*)d_in[1];   // (512, 4096)
    const float* V = (const float*)d_in[2];   // (512, 4096)
    float* out = (float*)d_out;

    char* ws = (char*)d_ws;                    // 48 MB used
    bf16_t* Wt = (bf16_t*)(ws);                            // (4096,4096) W^T
    bf16_t* Kt = (bf16_t*)(ws + (size_t)32 * 1024 * 1024); // (4096,512) K^T
    bf16_t* Kb = (bf16_t*)(ws + (size_t)36 * 1024 * 1024); // (512,4096) K
    bf16_t* Vt = (bf16_t*)(ws + (size_t)40 * 1024 * 1024); // (4096,512) V^T
    bf16_t* Rt = (bf16_t*)(ws + (size_t)44 * 1024 * 1024); // (4096,512) R^T

    t_conv_w <<<dim3(64, 64),    256, 0, stream>>>(W, Wt);
    t_conv_kv<<<dim3(64, 8, 2),  256, 0, stream>>>(K, V, Kt, Kb, Vt);
    k1_residual<<<dim3(32, 8),   256, 0, stream>>>(Wt, Kb, Vt, Rt);
    k2_update  <<<dim3(32, 32),  256, 0, stream>>>(Kt, Rt, W, out);
}

// Round 5
// 217.723 us; speedup vs baseline: 1.1131x; 1.1131x over previous
//
#include <hip/hip_runtime.h>
#include <hip/hip_bf16.h>

// OneStep: out = W - c * K^T (K W - V),  c = 0.2/(CTX*D) = 9.5367431640625e-8
// W:(4096,4096) K:(512,4096) V:(512,4096) fp32 -> out (4096,4096) fp32.
// bf16 MFMA w/ fp32 acc => absmax 2.441e-4 = 1 bf16 ulp (threshold 1.69e-3).
//
// R4 post-mortem: k1's BK=64 made LDS row stride 128 B == 0 mod 128 B -> all
// 16 l15-lanes hit the same 4 banks (9.4e6 conflicts, 48 cyc/b128 extra), and
// grid 256 = 1 block/CU (occupancy 10%) exposed every barrier drain.
// R5: k1 rebuilt as barrier-free within-block K-split: 4 waves x private
// K-range x private LDS staging (stride 64 B, conflict-free), explicit
// s_waitcnt vmcnt(0) instead of __syncthreads in the hot loop; 64x64/wave
// (32 MFMA : 8 ds_read_b128); grid 512 = 2 blocks/CU; end reduction via LDS
// aliased over dead staging.

typedef __bf16 bf16_t;
typedef __bf16 bf16x8 __attribute__((ext_vector_type(8)));
typedef float f32x4 __attribute__((ext_vector_type(4)));

#define D_DIM 4096
#define CTX_N 512
#define UPD_SCALE 9.5367431640625e-8f

__device__ __forceinline__ void gld16(const bf16_t* g, bf16_t* l) {
    __builtin_amdgcn_global_load_lds(
        (const __attribute__((address_space(1))) void*)g,
        (__attribute__((address_space(3))) void*)l, 16, 0, 0);
}

// ---- transpose+convert body: src (M x N) fp32 -> dstT (N x M) bf16
//      [+ dstN (M x N) bf16].  64x64 tiles, pad-65 LDS (2-way = free). ----
__device__ __forceinline__ void t_body(
    const float* __restrict__ src, bf16_t* __restrict__ dstT,
    bf16_t* __restrict__ dstN, int M, int N)
{
    __shared__ float tile[64 * 65];
    const int tid = threadIdx.x;
    const int C0 = blockIdx.x * 64;   // col base (N dim)
    const int R0 = blockIdx.y * 64;   // row base (M dim)
    const int r  = tid >> 2, cs = (tid & 3) * 16;

    const float* s = src + (size_t)(R0 + r) * N + C0 + cs;
    float f[16];
#pragma unroll
    for (int u = 0; u < 4; ++u) {
        const float4 v = ((const float4*)s)[u];
        f[4 * u + 0] = v.x; f[4 * u + 1] = v.y; f[4 * u + 2] = v.z; f[4 * u + 3] = v.w;
    }
#pragma unroll
    for (int u = 0; u < 16; ++u) tile[r * 65 + cs + u] = f[u];

    if (dstN) {
        bf16x8 v0, v1;
#pragma unroll
        for (int u = 0; u < 8; ++u) { v0[u] = (bf16_t)f[u]; v1[u] = (bf16_t)f[8 + u]; }
        bf16_t* d = dstN + (size_t)(R0 + r) * N + C0 + cs;
        *(bf16x8*)d = v0; *(bf16x8*)(d + 8) = v1;
    }
    __syncthreads();

    bf16x8 o0, o1;
#pragma unroll
    for (int u = 0; u < 8; ++u) {
        o0[u] = (bf16_t)tile[(cs + u) * 65 + r];
        o1[u] = (bf16_t)tile[(cs + 8 + u) * 65 + r];
    }
    bf16_t* d = dstT + (size_t)(C0 + r) * M + R0 + cs;
    *(bf16x8*)d = o0; *(bf16x8*)(d + 8) = o1;
}

__global__ __launch_bounds__(256) void t_conv_w(
    const float* __restrict__ W, bf16_t* __restrict__ Wt)
{
    t_body(W, Wt, nullptr, D_DIM, D_DIM);
}

__global__ __launch_bounds__(256) void t_conv_kv(
    const float* __restrict__ K, const float* __restrict__ V,
    bf16_t* __restrict__ Kt, bf16_t* __restrict__ Kb, bf16_t* __restrict__ Vt)
{
    if (blockIdx.z == 0) t_body(K, Kt, Kb, CTX_N, D_DIM);
    else                 t_body(V, Vt, nullptr, CTX_N, D_DIM);
}

// MFMA 16x16x32 bf16 (m89/m91): A/B frag: row=lane&15, k=quad*8+j (8 bf16);
// C/D: col=lane&15, row=quad*4+reg.  D[m][n] = sum_k A(m,k)*B(n,k).

// ---- K1: Rt[j][c] = sum_k Wt[j][k]*Kb[c][k] - Vt[j][c]  (4096 x 512) ----
// Barrier-free K-split: wave w owns k in [w*1024, w*1024+1024), 64x64 tile,
// private LDS staging (As/Bs 4 KB each, row stride 64 B). grid (64 j, 8 c):
// id%8 = j%8 pins the 8 c-sharers of a Wt slice to one XCD.
__global__ __launch_bounds__(256) void k1_residual(
    const bf16_t* __restrict__ Wt, const bf16_t* __restrict__ Kb,
    const bf16_t* __restrict__ Vt, bf16_t* __restrict__ Rt)
{
    __shared__ __align__(16) char smem[32768];  // staging; ep aliases it after

    const int tid = threadIdx.x, wave = tid >> 6, lane = tid & 63;
    const int j0 = blockIdx.x * 64, c0 = blockIdx.y * 64;
    const int l15 = lane & 15, quad = lane >> 4;
    const int kw = wave * 1024;

    bf16_t* As = (bf16_t*)(smem + wave * 4096);          // [64][32]
    bf16_t* Bs = (bf16_t*)(smem + 16384 + wave * 4096);  // [64][32]

    f32x4 acc[4][4] = {};

    const int srow = lane >> 2, sseg = (lane & 3) * 8;   // 16 rows / gld16 call
    const bf16_t* ga = Wt + (size_t)(j0 + srow) * D_DIM + kw + sseg;
    const bf16_t* gb = Kb + (size_t)(c0 + srow) * D_DIM + kw + sseg;
    bf16_t* la = As + lane * 8;   // lane*16 B
    bf16_t* lb = Bs + lane * 8;

    for (int i = 0; i < 32; ++i) {
        const int ko = i * 32;
#pragma unroll
        for (int c = 0; c < 4; ++c) {
            gld16(ga + ko + (size_t)(c * 16) * D_DIM, la + c * 512);
            gld16(gb + ko + (size_t)(c * 16) * D_DIM, lb + c * 512);
        }
        __builtin_amdgcn_s_waitcnt(0x0f70);  // vmcnt(0), ignore exp/lgkm
        bf16x8 a[4], b[4];
#pragma unroll
        for (int mi = 0; mi < 4; ++mi)
            a[mi] = *(const bf16x8*)(As + (mi * 16 + l15) * 32 + quad * 8);
#pragma unroll
        for (int ni = 0; ni < 4; ++ni)
            b[ni] = *(const bf16x8*)(Bs + (ni * 16 + l15) * 32 + quad * 8);
#pragma unroll
        for (int mi = 0; mi < 4; ++mi)
#pragma unroll
            for (int ni = 0; ni < 4; ++ni)
                acc[mi][ni] = __builtin_amdgcn_mfma_f32_16x16x32_bf16(
                    a[mi], b[ni], acc[mi][ni], 0, 0, 0);
    }

    // Cross-wave reduction: ep[64][68] f32 (17.4 KB) aliases dead staging.
    float* ep = (float*)smem;
    __syncthreads();
#pragma unroll
    for (int w = 0; w < 4; ++w) {
        if (wave == w) {
#pragma unroll
            for (int mi = 0; mi < 4; ++mi)
#pragma unroll
                for (int ni = 0; ni < 4; ++ni)
#pragma unroll
                    for (int r = 0; r < 4; ++r) {
                        const int row = mi * 16 + quad * 4 + r;
                        const int col = ni * 16 + l15;
                        if (w == 0) ep[row * 68 + col]  = acc[mi][ni][r];
                        else        ep[row * 68 + col] += acc[mi][ni][r];
                    }
        }
        __syncthreads();
    }

    // Epilogue: Rt = ep - Vt, vectorized.
    {
        const int row = tid >> 2, cs = (tid & 3) * 16;
        const size_t rbase = (size_t)(j0 + row) * CTX_N + c0 + cs;
        float e[16];
#pragma unroll
        for (int u = 0; u < 4; ++u) {
            const float4 v = ((const float4*)(ep + row * 68 + cs))[u];
            e[4 * u + 0] = v.x; e[4 * u + 1] = v.y;
            e[4 * u + 2] = v.z; e[4 * u + 3] = v.w;
        }
        const bf16x8 v0 = *(const bf16x8*)(Vt + rbase);
        const bf16x8 v1 = *(const bf16x8*)(Vt + rbase + 8);
        bf16x8 o0, o1;
#pragma unroll
        for (int u = 0; u < 8; ++u) {
            o0[u] = (bf16_t)(e[u]     - (float)v0[u]);
            o1[u] = (bf16_t)(e[8 + u] - (float)v1[u]);
        }
        *(bf16x8*)(Rt + rbase)     = o0;
        *(bf16x8*)(Rt + rbase + 8) = o1;
    }
}

// ---- K2: out[i][j] = W[i][j] - c * sum_c Kt[i][c]*Rt[j][c]  (4096x4096) ----
// 128x128 tile, BK=32, 4 waves of 64x64 (m93/m97 structure), 1024 blocks.
// Epilogue: acc -> ep[64][132] -> float4 W load + float4 out store.
__global__ __launch_bounds__(256) void k2_update(
    const bf16_t* __restrict__ Kt, const bf16_t* __restrict__ Rt,
    const float* __restrict__ W, float* __restrict__ out)
{
    __shared__ __align__(16) bf16_t As[128 * 32];  // Kt rows (i,c) 8 KB
    __shared__ __align__(16) bf16_t Bs[128 * 32];  // Rt rows (j,c) 8 KB
    __shared__ __align__(16) float  ep[64 * 132];  // 33 KB epilogue transpose

    const int tid = threadIdx.x;
    const int j0 = blockIdx.x * 128, i0 = blockIdx.y * 128;
    const int lane = tid & 63, wave = tid >> 6;
    const int wi = (wave >> 1) * 64, wj = (wave & 1) * 64;
    const int l15 = lane & 15, quad = lane >> 4;

    f32x4 acc[4][4] = {};

    const bf16_t* ga = Kt + (size_t)(i0 + (tid >> 2)) * CTX_N + (tid & 3) * 8;
    const bf16_t* gb = Rt + (size_t)(j0 + (tid >> 2)) * CTX_N + (tid & 3) * 8;
    bf16_t* la = (bf16_t*)((char*)As + tid * 16);
    bf16_t* lb = (bf16_t*)((char*)Bs + tid * 16);

    for (int cc = 0; cc < CTX_N; cc += 32) {
        gld16(ga + cc, la);
        gld16(ga + cc + (size_t)64 * CTX_N, la + 64 * 32);
        gld16(gb + cc, lb);
        gld16(gb + cc + (size_t)64 * CTX_N, lb + 64 * 32);
        __syncthreads();
        bf16x8 a[4], b[4];
#pragma unroll
        for (int mi = 0; mi < 4; ++mi)
            a[mi] = *(const bf16x8*)(As + (wi + mi * 16 + l15) * 32 + quad * 8);
#pragma unroll
        for (int ni = 0; ni < 4; ++ni)
            b[ni] = *(const bf16x8*)(Bs + (wj + ni * 16 + l15) * 32 + quad * 8);
#pragma unroll
        for (int mi = 0; mi < 4; ++mi)
#pragma unroll
            for (int ni = 0; ni < 4; ++ni)
                acc[mi][ni] = __builtin_amdgcn_mfma_f32_16x16x32_bf16(
                    a[mi], b[ni], acc[mi][ni], 0, 0, 0);
        __syncthreads();
    }

    // Epilogue: two 64-row passes through ep.
#pragma unroll
    for (int p = 0; p < 2; ++p) {
        if ((wave >> 1) == p) {
#pragma unroll
            for (int mi = 0; mi < 4; ++mi)
#pragma unroll
                for (int ni = 0; ni < 4; ++ni)
#pragma unroll
                    for (int r = 0; r < 4; ++r)
                        ep[(mi * 16 + quad * 4 + r) * 132 + wj + ni * 16 + l15] =
                            acc[mi][ni][r];
        }
        __syncthreads();
        {
            const int row = tid >> 2, cb = (tid & 3) * 32;
            const float* wrow = W   + (size_t)(i0 + p * 64 + row) * D_DIM + j0 + cb;
            float*      orow = out + (size_t)(i0 + p * 64 + row) * D_DIM + j0 + cb;
            const float* erow = ep + row * 132 + cb;
#pragma unroll
            for (int u = 0; u < 8; ++u) {
                const float4 wv = ((const float4*)wrow)[u];
                const float4 ev = ((const float4*)erow)[u];
                float4 ov;
                ov.x = wv.x - UPD_SCALE * ev.x;
                ov.y = wv.y - UPD_SCALE * ev.y;
                ov.z = wv.z - UPD_SCALE * ev.z;
                ov.w = wv.w - UPD_SCALE * ev.w;
                ((float4*)orow)[u] = ov;
            }
        }
        __syncthreads();
    }
}

extern "C" void kernel_launch(void* const* d_in, const int* in_sizes, int n_in,
                              void* d_out, int out_size, void* d_ws, size_t ws_size,
                              hipStream_t stream) {
    const float* W = (const float*)d_in[0];   // (4096, 4096)
    const float* K = (const float*)d_in[1];   // (512, 4096)
    const float* V = (const float*)d_in[2];   // (512, 4096)
    float* out = (float*)d_out;

    char* ws = (char*)d_ws;                    // 48 MB used
    bf16_t* Wt = (bf16_t*)(ws);                            // (4096,4096) W^T
    bf16_t* Kt = (bf16_t*)(ws + (size_t)32 * 1024 * 1024); // (4096,512) K^T
    bf16_t* Kb = (bf16_t*)(ws + (size_t)36 * 1024 * 1024); // (512,4096) K
    bf16_t* Vt = (bf16_t*)(ws + (size_t)40 * 1024 * 1024); // (4096,512) V^T
    bf16_t* Rt = (bf16_t*)(ws + (size_t)44 * 1024 * 1024); // (4096,512) R^T

    t_conv_w <<<dim3(64, 64),    256, 0, stream>>>(W, Wt);
    t_conv_kv<<<dim3(64, 8, 2),  256, 0, stream>>>(K, V, Kt, Kb, Vt);
    k1_residual<<<dim3(64, 8),   256, 0, stream>>>(Wt, Kb, Vt, Rt);
    k2_update  <<<dim3(32, 32),  256, 0, stream>>>(Kt, Rt, W, out);
}

// Round 6
// 210.745 us; speedup vs baseline: 1.1499x; 1.0331x over previous
//
#include <hip/hip_runtime.h>
#include <hip/hip_bf16.h>

// OneStep: out = W - c * K^T (K W - V),  c = 0.2/(CTX*D) = 9.5367431640625e-8
// W:(4096,4096) K:(512,4096) V:(512,4096) fp32 -> out (4096,4096) fp32.
// bf16 MFMA w/ fp32 acc => absmax 2.441e-4 = 1 bf16 ulp (threshold 1.69e-3).
//
// R5 post-mortem: k2 stuck at 56 us / 2.17 TB/s: 50 KB LDS (33 KB epilogue
// buffer) capped occupancy at 3 blocks/CU; Little's law at 12 waves x 8
// float4 in flight predicts exactly the measured ~2.2 TB/s on the epilogue.
// R6: alias the epilogue transpose buffer over dead staging LDS (4 passes of
// 32 rows, 16.9 KB total) -> ~20 waves/CU; prefetch W per pass; k1 gets a
// split vmcnt(4)/vmcnt(0) staging wait; transposes merged into one launch.

typedef __bf16 bf16_t;
typedef __bf16 bf16x8 __attribute__((ext_vector_type(8)));
typedef float f32x4 __attribute__((ext_vector_type(4)));

#define D_DIM 4096
#define CTX_N 512
#define UPD_SCALE 9.5367431640625e-8f

__device__ __forceinline__ void gld16(const bf16_t* g, bf16_t* l) {
    __builtin_amdgcn_global_load_lds(
        (const __attribute__((address_space(1))) void*)g,
        (__attribute__((address_space(3))) void*)l, 16, 0, 0);
}

// ---- transpose+convert body: src (M x N) fp32 -> dstT (N x M) bf16
//      [+ dstN (M x N) bf16].  64x64 tile at (bx,by); pad-65 (2-way = free).
__device__ __forceinline__ void t_body(
    float* tile, const float* __restrict__ src, bf16_t* __restrict__ dstT,
    bf16_t* __restrict__ dstN, int N, int bx, int by)
{
    const int tid = threadIdx.x;
    const int C0 = bx * 64, R0 = by * 64;
    const int r  = tid >> 2, cs = (tid & 3) * 16;

    const float* s = src + (size_t)(R0 + r) * N + C0 + cs;
    float f[16];
#pragma unroll
    for (int u = 0; u < 4; ++u) {
        const float4 v = ((const float4*)s)[u];
        f[4 * u + 0] = v.x; f[4 * u + 1] = v.y; f[4 * u + 2] = v.z; f[4 * u + 3] = v.w;
    }
#pragma unroll
    for (int u = 0; u < 16; ++u) tile[r * 65 + cs + u] = f[u];

    if (dstN) {
        bf16x8 v0, v1;
#pragma unroll
        for (int u = 0; u < 8; ++u) { v0[u] = (bf16_t)f[u]; v1[u] = (bf16_t)f[8 + u]; }
        bf16_t* d = dstN + (size_t)(R0 + r) * N + C0 + cs;
        *(bf16x8*)d = v0; *(bf16x8*)(d + 8) = v1;
    }
    __syncthreads();

    bf16x8 o0, o1;
#pragma unroll
    for (int u = 0; u < 8; ++u) {
        o0[u] = (bf16_t)tile[(cs + u) * 65 + r];
        o1[u] = (bf16_t)tile[(cs + 8 + u) * 65 + r];
    }
    // M = 512 or 4096; dstT row length is M
    bf16_t* d = dstT + (size_t)(C0 + r) * (dstN || N == D_DIM ? 0 : 0);  // placeholder avoided below
    (void)d;
    // (row length passed implicitly: W -> D_DIM, K/V -> D_DIM rows of len M)
    // handled by caller-specific stride argument instead:
    // -- replaced by explicit stride write below --
    // (kept simple: write with stride M passed via N? see t_all)
    // NOTE: actual store done in t_body_store
    {
        // stride of dstT rows = M (source row count)
        // caller guarantees dstT is (N x M)
    }
    // store:
    // (we need M; recompute from caller via template-free param)
    // -- see t_all which passes M through 'Mrows'
    // This branch never taken; real store below in t_body2.
    ;
}

// Full body with explicit M (dstT is N x M).
__device__ __forceinline__ void t_body2(
    float* tile, const float* __restrict__ src, bf16_t* __restrict__ dstT,
    bf16_t* __restrict__ dstN, int M, int N, int bx, int by)
{
    const int tid = threadIdx.x;
    const int C0 = bx * 64, R0 = by * 64;
    const int r  = tid >> 2, cs = (tid & 3) * 16;

    const float* s = src + (size_t)(R0 + r) * N + C0 + cs;
    float f[16];
#pragma unroll
    for (int u = 0; u < 4; ++u) {
        const float4 v = ((const float4*)s)[u];
        f[4 * u + 0] = v.x; f[4 * u + 1] = v.y; f[4 * u + 2] = v.z; f[4 * u + 3] = v.w;
    }
#pragma unroll
    for (int u = 0; u < 16; ++u) tile[r * 65 + cs + u] = f[u];

    if (dstN) {
        bf16x8 v0, v1;
#pragma unroll
        for (int u = 0; u < 8; ++u) { v0[u] = (bf16_t)f[u]; v1[u] = (bf16_t)f[8 + u]; }
        bf16_t* d = dstN + (size_t)(R0 + r) * N + C0 + cs;
        *(bf16x8*)d = v0; *(bf16x8*)(d + 8) = v1;
    }
    __syncthreads();

    bf16x8 o0, o1;
#pragma unroll
    for (int u = 0; u < 8; ++u) {
        o0[u] = (bf16_t)tile[(cs + u) * 65 + r];
        o1[u] = (bf16_t)tile[(cs + 8 + u) * 65 + r];
    }
    bf16_t* d = dstT + (size_t)(C0 + r) * M + R0 + cs;
    *(bf16x8*)d = o0; *(bf16x8*)(d + 8) = o1;
}

// One launch for all three transposes: y<64 -> W, 64..71 -> K(+Kb), 72..79 -> V
__global__ __launch_bounds__(256) void t_all(
    const float* __restrict__ W, const float* __restrict__ K,
    const float* __restrict__ V, bf16_t* __restrict__ Wt,
    bf16_t* __restrict__ Kt, bf16_t* __restrict__ Kb, bf16_t* __restrict__ Vt)
{
    __shared__ float tile[64 * 65];
    const int y = blockIdx.y;
    if (y < 64)      t_body2(tile, W, Wt, nullptr, D_DIM, D_DIM, blockIdx.x, y);
    else if (y < 72) t_body2(tile, K, Kt, Kb,      CTX_N, D_DIM, blockIdx.x, y - 64);
    else             t_body2(tile, V, Vt, nullptr, CTX_N, D_DIM, blockIdx.x, y - 72);
}

// MFMA 16x16x32 bf16 (m89/m91): A/B frag: row=lane&15, k=quad*8+j (8 bf16);
// C/D: col=lane&15, row=quad*4+reg.  D[m][n] = sum_k A(m,k)*B(n,k).

// ---- K1: Rt[j][c] = sum_k Wt[j][k]*Kb[c][k] - Vt[j][c]  (4096 x 512) ----
// Barrier-free K-split: wave w owns k in [w*1024, w*1024+1024), 64x64 tile,
// private LDS staging (stride 64 B, conflict-free). Split vmcnt(4)/vmcnt(0)
// waits hide half the staging latency. grid (64 j, 8 c): id%8 = j%8 pins the
// 8 c-sharers of a Wt slice to one XCD.
__global__ __launch_bounds__(256) void k1_residual(
    const bf16_t* __restrict__ Wt, const bf16_t* __restrict__ Kb,
    const bf16_t* __restrict__ Vt, bf16_t* __restrict__ Rt)
{
    __shared__ __align__(16) char smem[32768];  // staging; ep aliases it after

    const int tid = threadIdx.x, wave = tid >> 6, lane = tid & 63;
    const int j0 = blockIdx.x * 64, c0 = blockIdx.y * 64;
    const int l15 = lane & 15, quad = lane >> 4;
    const int kw = wave * 1024;

    bf16_t* As = (bf16_t*)(smem + wave * 4096);          // [64][32]
    bf16_t* Bs = (bf16_t*)(smem + 16384 + wave * 4096);  // [64][32]

    f32x4 acc[4][4] = {};

    const int srow = lane >> 2, sseg = (lane & 3) * 8;   // 16 rows / gld16 call
    const bf16_t* ga = Wt + (size_t)(j0 + srow) * D_DIM + kw + sseg;
    const bf16_t* gb = Kb + (size_t)(c0 + srow) * D_DIM + kw + sseg;
    bf16_t* la = As + lane * 8;   // lane*16 B
    bf16_t* lb = Bs + lane * 8;

    for (int i = 0; i < 32; ++i) {
        const int ko = i * 32;
#pragma unroll
        for (int c = 0; c < 4; ++c)
            gld16(ga + ko + (size_t)(c * 16) * D_DIM, la + c * 512);
#pragma unroll
        for (int c = 0; c < 4; ++c)
            gld16(gb + ko + (size_t)(c * 16) * D_DIM, lb + c * 512);
        __builtin_amdgcn_s_waitcnt(0x0f74);  // vmcnt(4): the 4 A-loads done
        bf16x8 a[4];
#pragma unroll
        for (int mi = 0; mi < 4; ++mi)
            a[mi] = *(const bf16x8*)(As + (mi * 16 + l15) * 32 + quad * 8);
        __builtin_amdgcn_s_waitcnt(0x0f70);  // vmcnt(0): B-loads done
        bf16x8 b[4];
#pragma unroll
        for (int ni = 0; ni < 4; ++ni)
            b[ni] = *(const bf16x8*)(Bs + (ni * 16 + l15) * 32 + quad * 8);
#pragma unroll
        for (int mi = 0; mi < 4; ++mi)
#pragma unroll
            for (int ni = 0; ni < 4; ++ni)
                acc[mi][ni] = __builtin_amdgcn_mfma_f32_16x16x32_bf16(
                    a[mi], b[ni], acc[mi][ni], 0, 0, 0);
    }

    // Cross-wave reduction: ep[64][68] f32 (17.4 KB) aliases dead staging.
    float* ep = (float*)smem;
    __syncthreads();
#pragma unroll
    for (int w = 0; w < 4; ++w) {
        if (wave == w) {
#pragma unroll
            for (int mi = 0; mi < 4; ++mi)
#pragma unroll
                for (int ni = 0; ni < 4; ++ni)
#pragma unroll
                    for (int r = 0; r < 4; ++r) {
                        const int row = mi * 16 + quad * 4 + r;
                        const int col = ni * 16 + l15;
                        if (w == 0) ep[row * 68 + col]  = acc[mi][ni][r];
                        else        ep[row * 68 + col] += acc[mi][ni][r];
                    }
        }
        __syncthreads();
    }

    // Epilogue: Rt = ep - Vt, vectorized.
    {
        const int row = tid >> 2, cs = (tid & 3) * 16;
        const size_t rbase = (size_t)(j0 + row) * CTX_N + c0 + cs;
        float e[16];
#pragma unroll
        for (int u = 0; u < 4; ++u) {
            const float4 v = ((const float4*)(ep + row * 68 + cs))[u];
            e[4 * u + 0] = v.x; e[4 * u + 1] = v.y;
            e[4 * u + 2] = v.z; e[4 * u + 3] = v.w;
        }
        const bf16x8 v0 = *(const bf16x8*)(Vt + rbase);
        const bf16x8 v1 = *(const bf16x8*)(Vt + rbase + 8);
        bf16x8 o0, o1;
#pragma unroll
        for (int u = 0; u < 8; ++u) {
            o0[u] = (bf16_t)(e[u]     - (float)v0[u]);
            o1[u] = (bf16_t)(e[8 + u] - (float)v1[u]);
        }
        *(bf16x8*)(Rt + rbase)     = o0;
        *(bf16x8*)(Rt + rbase + 8) = o1;
    }
}

// ---- K2: out[i][j] = W[i][j] - c * sum_c Kt[i][c]*Rt[j][c]  (4096x4096) ----
// 128x128 tile, BK=32, 4 waves of 64x64. LDS: 16.9 KB total — epilogue
// transpose buffer ep[32][132] ALIASES the dead staging, done in 4 passes of
// 32 rows with per-pass W float4 prefetch. ~20 waves/CU (VGPR-limited).
__global__ __launch_bounds__(256) void k2_update(
    const bf16_t* __restrict__ Kt, const bf16_t* __restrict__ Rt,
    const float* __restrict__ W, float* __restrict__ out)
{
    __shared__ __align__(16) char smem[32 * 132 * 4];  // 16896 B

    bf16_t* As = (bf16_t*)smem;            // [128][32] 8 KB (K-loop)
    bf16_t* Bs = (bf16_t*)(smem + 8192);   // [128][32] 8 KB (K-loop)
    float*  ep = (float*)smem;             // [32][132] (epilogue, aliased)

    const int tid = threadIdx.x;
    const int j0 = blockIdx.x * 128, i0 = blockIdx.y * 128;
    const int lane = tid & 63, wave = tid >> 6;
    const int wi = (wave >> 1) * 64, wj = (wave & 1) * 64;
    const int l15 = lane & 15, quad = lane >> 4;

    f32x4 acc[4][4] = {};

    const bf16_t* ga = Kt + (size_t)(i0 + (tid >> 2)) * CTX_N + (tid & 3) * 8;
    const bf16_t* gb = Rt + (size_t)(j0 + (tid >> 2)) * CTX_N + (tid & 3) * 8;
    bf16_t* la = (bf16_t*)(smem + tid * 16);
    bf16_t* lb = (bf16_t*)(smem + 8192 + tid * 16);

    for (int cc = 0; cc < CTX_N; cc += 32) {
        gld16(ga + cc, la);
        gld16(ga + cc + (size_t)64 * CTX_N, la + 64 * 32);
        gld16(gb + cc, lb);
        gld16(gb + cc + (size_t)64 * CTX_N, lb + 64 * 32);
        __syncthreads();
        bf16x8 a[4], b[4];
#pragma unroll
        for (int mi = 0; mi < 4; ++mi)
            a[mi] = *(const bf16x8*)(As + (wi + mi * 16 + l15) * 32 + quad * 8);
#pragma unroll
        for (int ni = 0; ni < 4; ++ni)
            b[ni] = *(const bf16x8*)(Bs + (wj + ni * 16 + l15) * 32 + quad * 8);
#pragma unroll
        for (int mi = 0; mi < 4; ++mi)
#pragma unroll
            for (int ni = 0; ni < 4; ++ni)
                acc[mi][ni] = __builtin_amdgcn_mfma_f32_16x16x32_bf16(
                    a[mi], b[ni], acc[mi][ni], 0, 0, 0);
        __syncthreads();
    }

    // Epilogue: 4 passes x 32 rows through ep[32][132] (aliases staging).
    const int row = tid >> 3;          // 0..31
    const int cb  = (tid & 7) * 16;    // 0,16,...,112
#pragma unroll
    for (int p = 0; p < 4; ++p) {
        // Prefetch W for this pass (drains during the LDS transpose+barrier).
        const float* wrow = W + (size_t)(i0 + p * 32 + row) * D_DIM + j0 + cb;
        float4 wv[4];
#pragma unroll
        for (int u = 0; u < 4; ++u) wv[u] = ((const float4*)wrow)[u];

        if ((wave >> 1) == (p >> 1)) {
#pragma unroll
            for (int mh = 0; mh < 2; ++mh) {
                const int mi = (p & 1) * 2 + mh;
#pragma unroll
                for (int ni = 0; ni < 4; ++ni)
#pragma unroll
                    for (int r = 0; r < 4; ++r)
                        ep[(mh * 16 + quad * 4 + r) * 132 + wj + ni * 16 + l15] =
                            acc[mi][ni][r];
            }
        }
        __syncthreads();
        {
            float* orow = out + (size_t)(i0 + p * 32 + row) * D_DIM + j0 + cb;
            const float* erow = ep + row * 132 + cb;
#pragma unroll
            for (int u = 0; u < 4; ++u) {
                const float4 ev = ((const float4*)erow)[u];
                float4 ov;
                ov.x = wv[u].x - UPD_SCALE * ev.x;
                ov.y = wv[u].y - UPD_SCALE * ev.y;
                ov.z = wv[u].z - UPD_SCALE * ev.z;
                ov.w = wv[u].w - UPD_SCALE * ev.w;
                ((float4*)orow)[u] = ov;
            }
        }
        __syncthreads();
    }
}

extern "C" void kernel_launch(void* const* d_in, const int* in_sizes, int n_in,
                              void* d_out, int out_size, void* d_ws, size_t ws_size,
                              hipStream_t stream) {
    const float* W = (const float*)d_in[0];   // (4096, 4096)
    const float* K = (const float*)d_in[1];   // (512, 4096)
    const float* V = (const float*)d_in[2];   // (512, 4096)
    float* out = (float*)d_out;

    char* ws = (char*)d_ws;                    // 48 MB used
    bf16_t* Wt = (bf16_t*)(ws);                            // (4096,4096) W^T
    bf16_t* Kt = (bf16_t*)(ws + (size_t)32 * 1024 * 1024); // (4096,512) K^T
    bf16_t* Kb = (bf16_t*)(ws + (size_t)36 * 1024 * 1024); // (512,4096) K
    bf16_t* Vt = (bf16_t*)(ws + (size_t)40 * 1024 * 1024); // (4096,512) V^T
    bf16_t* Rt = (bf16_t*)(ws + (size_t)44 * 1024 * 1024); // (4096,512) R^T

    t_all      <<<dim3(64, 80), 256, 0, stream>>>(W, K, V, Wt, Kt, Kb, Vt);
    k1_residual<<<dim3(64, 8),  256, 0, stream>>>(Wt, Kb, Vt, Rt);
    k2_update  <<<dim3(32, 32), 256, 0, stream>>>(Kt, Rt, W, out);
}